// Round 16
// baseline (618.428 us; speedup 1.0000x reference)
//
#include <hip/hip_runtime.h>
#include <math.h>

// Transformer-XL tower. bf16 MFMA GEMMs (BK=64 ring pipeline auto-sized to 48KB LDS,
// counted vmcnt + T2 swizzle + 2D-chunked XCD mapping, split-K EVERYWHERE, z-batched)
// + MFMA flash attention (split-j + merge, async K/R staging).
// L=4, B=2, S=512, M=512, D=1024, H=16, DK=64, FF=4096, T=S+M=1024
#define CB  2
#define CS  512
#define CM  512
#define CD  1024
#define CH  16
#define CDK 64
#define CFF 4096
#define CL  4
#define CT  1024

using short8 = __attribute__((ext_vector_type(8))) short;
using f32x4  = __attribute__((ext_vector_type(4))) float;

__device__ __forceinline__ ushort f2bf(float x) {
    union { float f; unsigned int u; } c; c.f = x;
    unsigned int u = c.u + 0x7FFFu + ((c.u >> 16) & 1u);
    return (ushort)(u >> 16);
}
__device__ __forceinline__ float bf2f(ushort h) {
    union { unsigned int u; float f; } c; c.u = ((unsigned int)h) << 16;
    return c.f;
}

// async global->LDS, 16B per lane; dest = wave-uniform base + lane*16
#define GLD16(gsrc, ldst) \
    __builtin_amdgcn_global_load_lds((const __attribute__((address_space(1))) void*)(gsrc), \
                                     (__attribute__((address_space(3))) void*)(ldst), 16, 0, 0)

// ---------------- positional encodings -> bf16 [T][D]
__global__ void pos_kernel(ushort* __restrict__ pos) {
    int idx = blockIdx.x * blockDim.x + threadIdx.x;   // T * D/2
    if (idx >= CT * (CD / 2)) return;
    int i = idx % (CD / 2);
    int t = idx / (CD / 2);
    float p = (float)(CT - 1 - t);
    float inv = __expf(-(float)i * (9.210340371976184f / 512.0f));
    float ang = p * inv;
    pos[(size_t)t * CD + i]          = f2bf(sinf(ang));
    pos[(size_t)t * CD + i + CD / 2] = f2bf(cosf(ang));
}

// ---------------- elementwise f32 -> bf16 (n8 = count/8)
__global__ void cvt_bf16_kernel(const float* __restrict__ in, ushort* __restrict__ out, int n8) {
    int i = blockIdx.x * blockDim.x + threadIdx.x;
    if (i >= n8) return;
    float4 a = ((const float4*)in)[i * 2];
    float4 c = ((const float4*)in)[i * 2 + 1];
    union { ushort us[8]; uint4 q; } pk;
    pk.us[0] = f2bf(a.x); pk.us[1] = f2bf(a.y); pk.us[2] = f2bf(a.z); pk.us[3] = f2bf(a.w);
    pk.us[4] = f2bf(c.x); pk.us[5] = f2bf(c.y); pk.us[6] = f2bf(c.z); pk.us[7] = f2bf(c.w);
    ((uint4*)out)[i] = pk.q;
}

// ---------------- combine split-K partials: out_bf16 = [relu](p0 + p1 + bias[col])
__global__ __launch_bounds__(256)
void combine_bf16(const float* __restrict__ p0, const float* __restrict__ p1,
                  const float* __restrict__ bias, int ncols8,
                  ushort* __restrict__ out, int n8, int relu) {
    int i = blockIdx.x * blockDim.x + threadIdx.x;
    if (i >= n8) return;
    float4 a0 = ((const float4*)p0)[2 * i];
    float4 a1 = ((const float4*)p0)[2 * i + 1];
    float4 b0 = ((const float4*)p1)[2 * i];
    float4 b1 = ((const float4*)p1)[2 * i + 1];
    float r[8] = {a0.x + b0.x, a0.y + b0.y, a0.z + b0.z, a0.w + b0.w,
                  a1.x + b1.x, a1.y + b1.y, a1.z + b1.z, a1.w + b1.w};
    if (bias) {
        const int cb = (i % ncols8) * 8;
        float4 v0 = *(const float4*)&bias[cb];
        float4 v1 = *(const float4*)&bias[cb + 4];
        r[0] += v0.x; r[1] += v0.y; r[2] += v0.z; r[3] += v0.w;
        r[4] += v1.x; r[5] += v1.y; r[6] += v1.z; r[7] += v1.w;
    }
    union { ushort us[8]; uint4 q; } pk;
    #pragma unroll
    for (int e = 0; e < 8; ++e) {
        float v = relu ? fmaxf(r[e], 0.f) : r[e];
        pk.us[e] = f2bf(v);
    }
    ((uint4*)out)[i] = pk.q;
}

// ---------------- transpose+convert the 5 DxD weight families in one launch
// z = wi*CL + l, wi in {0:Wq(*0.125),1:Wk,2:Wv,3:Wr,4:Wo}
__global__ __launch_bounds__(256)
void transpose_w5(const float* __restrict__ Wq, const float* __restrict__ Wk,
                  const float* __restrict__ Wv, const float* __restrict__ Wr,
                  const float* __restrict__ Wo,
                  ushort* __restrict__ wqkvT, ushort* __restrict__ wrT,
                  ushort* __restrict__ woT) {
    const size_t WD = (size_t)CD * CD;
    const int wi = blockIdx.z / CL, l = blockIdx.z % CL;
    const float* in;
    ushort* o;
    float sc = 1.0f;
    switch (wi) {
        case 0: in = Wq + l * WD; o = wqkvT + (size_t)l * 3 * WD; sc = 0.125f; break;
        case 1: in = Wk + l * WD; o = wqkvT + (size_t)l * 3 * WD + WD; break;
        case 2: in = Wv + l * WD; o = wqkvT + (size_t)l * 3 * WD + 2 * WD; break;
        case 3: in = Wr + l * WD; o = wrT + (size_t)l * WD; break;
        default: in = Wo + l * WD; o = woT + (size_t)l * WD; break;
    }
    __shared__ __align__(16) float t[64][68];
    const int n0 = blockIdx.x * 64, k0 = blockIdx.y * 64;
    const int tid = threadIdx.x;
    #pragma unroll
    for (int rep = 0; rep < 4; ++rep) {
        int lin = rep * 256 + tid;
        int r = lin >> 4, c4 = lin & 15;
        float4 v = *(const float4*)&in[(size_t)(k0 + r) * CD + n0 + c4 * 4];
        *(float4*)&t[r][c4 * 4] = v;
    }
    __syncthreads();
    #pragma unroll
    for (int rep = 0; rep < 2; ++rep) {
        int lin = rep * 256 + tid;
        int n = lin >> 3, kc = lin & 7;
        union { ushort us[8]; uint4 q; } pk;
        #pragma unroll
        for (int j = 0; j < 8; ++j) pk.us[j] = f2bf(t[kc * 8 + j][n] * sc);
        *(uint4*)&o[(size_t)(n0 + n) * CD + k0 + kc * 8] = pk.q;
    }
}

// ---------------- transpose+convert, z-batched (for W1/W2)
__global__ __launch_bounds__(256)
void transpose_cvt(const float* __restrict__ inb, ushort* __restrict__ outb,
                   int Kd, int Nc, size_t inz, size_t outz) {
    const float* in = inb + (size_t)blockIdx.z * inz;
    ushort* o = outb + (size_t)blockIdx.z * outz;
    __shared__ __align__(16) float t[64][68];
    const int n0 = blockIdx.x * 64, k0 = blockIdx.y * 64;
    const int tid = threadIdx.x;
    #pragma unroll
    for (int rep = 0; rep < 4; ++rep) {
        int lin = rep * 256 + tid;
        int r = lin >> 4, c4 = lin & 15;
        float4 v = *(const float4*)&in[(size_t)(k0 + r) * Nc + n0 + c4 * 4];
        *(float4*)&t[r][c4 * 4] = v;
    }
    __syncthreads();
    #pragma unroll
    for (int rep = 0; rep < 2; ++rep) {
        int lin = rep * 256 + tid;
        int n = lin >> 3, kc = lin & 7;
        union { ushort us[8]; uint4 q; } pk;
        #pragma unroll
        for (int j = 0; j < 8; ++j) pk.us[j] = f2bf(t[kc * 8 + j][n]);
        *(uint4*)&o[(size_t)(n0 + n) * Kd + k0 + kc * 8] = pk.q;
    }
}

// ---------------- bf16 MFMA GEMM: C[M,N] = A[M,K(lda)] @ Bt[N,K(lda)]^T
// BMxBN tile, BK=64, 4 waves (2x2); ring pipeline with counted vmcnt, ring depth
// chosen so LDS <= 48KB (3 blocks/CU). T2 XOR swizzle, 2D-chunked XCD mapping.
// blockIdx.z: offsets az/bz/cz (split-K or batch).
template<int BM, int BN>
__global__ __launch_bounds__(256)
void gemm_bf16(const ushort* __restrict__ A, const ushort* __restrict__ Bt,
               float* __restrict__ Cf, ushort* __restrict__ Cbf,
               int Nc, int Kd, int lda, int cw, int ch,
               size_t az, size_t bz, size_t cz,
               const float* __restrict__ bias, float scale, int relu)
{
    constexpr int FM = BM / 32, FN = BN / 32;
    constexpr int LPW = BM / 32 + BN / 32;        // global_load_lds per wave per step
    constexpr int STEPB = (BM + BN) * 64 * 2;     // LDS bytes per K-step
    constexpr int RING = (3 * STEPB <= 49152) ? 3 : 2;
    __shared__ __align__(16) ushort As[RING][BM * 64];
    __shared__ __align__(16) ushort Bs[RING][BN * 64];
    const int tid  = threadIdx.x;
    const int lane = tid & 63, w = tid >> 6;
    const int wr = w >> 1, wc = w & 1;
    const int lo4 = lane & 15, g = lane >> 4;
    // chunked XCD mapping (HW round-robins id%8 across XCDs)
    const int id  = blockIdx.y * gridDim.x + blockIdx.x;
    const int e = id & 7, q = id >> 3;
    const int ncx = gridDim.x / cw;
    const int col0 = ((e % ncx) * cw + q % cw) * BN;
    const int row0 = ((e / ncx) * ch + q / cw) * BM;
    const int zz = blockIdx.z;
    const ushort* Ab = A  + (size_t)row0 * lda + (size_t)zz * az;
    const ushort* Bb = Bt + (size_t)col0 * lda + (size_t)zz * bz;
    f32x4 acc[FM][FN];
    #pragma unroll
    for (int m = 0; m < FM; ++m)
        #pragma unroll
        for (int n = 0; n < FN; ++n) acc[m][n] = (f32x4){0.f, 0.f, 0.f, 0.f};

#define GSTAGE(buf, kk) do {                                                          \
        _Pragma("unroll")                                                             \
        for (int c = 0; c < BM / 32; ++c) {                                           \
            const int linw = (c * 4 + w) * 64;                                        \
            const int lin  = linw + lane;                                             \
            GLD16(Ab + (size_t)(lin >> 3) * lda + (kk) + ((lin ^ (lin >> 3)) & 7) * 8, \
                  &As[buf][linw * 8]);                                                \
        }                                                                             \
        _Pragma("unroll")                                                             \
        for (int c = 0; c < BN / 32; ++c) {                                           \
            const int linw = (c * 4 + w) * 64;                                        \
            const int lin  = linw + lane;                                             \
            GLD16(Bb + (size_t)(lin >> 3) * lda + (kk) + ((lin ^ (lin >> 3)) & 7) * 8, \
                  &Bs[buf][linw * 8]);                                                \
        }                                                                             \
    } while (0)

    const int nsteps = Kd / 64;   // always >= 8 in this kernel's uses
    GSTAGE(0, 0);
    GSTAGE(1, 64);
    if constexpr (RING == 3) GSTAGE(2, 128);
    int buf = 0;
    for (int s = 0; s < nsteps; ++s) {
        // B1: this step's loads landed (own outstanding <= RING-1 steps)
        asm volatile("s_waitcnt vmcnt(%0)" :: "n"((RING - 1) * LPW) : "memory");
        __builtin_amdgcn_s_barrier();
        __builtin_amdgcn_sched_barrier(0);
        short8 af[2][FM], bfr[2][FN];
        #pragma unroll
        for (int h2 = 0; h2 < 2; ++h2) {
            #pragma unroll
            for (int m = 0; m < FM; ++m) {
                const int ar = wr * (BM / 2) + m * 16 + lo4;
                af[h2][m] = *(const short8*)&As[buf][ar * 64 + ((((h2 << 2) + g) ^ (ar & 7)) << 3)];
            }
            #pragma unroll
            for (int n = 0; n < FN; ++n) {
                const int br = wc * (BN / 2) + n * 16 + lo4;
                bfr[h2][n] = *(const short8*)&Bs[buf][br * 64 + ((((h2 << 2) + g) ^ (br & 7)) << 3)];
            }
        }
        asm volatile("s_waitcnt lgkmcnt(0)" ::: "memory");
        __builtin_amdgcn_sched_barrier(0);
        __builtin_amdgcn_s_barrier();          // B2: all waves done reading buf
        if (s + RING < nsteps) GSTAGE(buf, (s + RING) * 64);   // refill freed buffer
        __builtin_amdgcn_s_setprio(1);
        #pragma unroll
        for (int h2 = 0; h2 < 2; ++h2)
            #pragma unroll
            for (int m = 0; m < FM; ++m)
                #pragma unroll
                for (int n = 0; n < FN; ++n)
                    acc[m][n] = __builtin_amdgcn_mfma_f32_16x16x32_bf16(
                        af[h2][m], bfr[h2][n], acc[m][n], 0, 0, 0);
        __builtin_amdgcn_s_setprio(0);
        buf = (buf == RING - 1) ? 0 : buf + 1;
    }
#undef GSTAGE

    float*  Cw  = Cf  ? Cf  + (size_t)zz * cz : nullptr;
    ushort* Cbw = Cbf ? Cbf + (size_t)zz * cz : nullptr;
    const int colbase = col0 + wc * (BN / 2) + lo4;
    const int rowbase = row0 + wr * (BM / 2) + (g << 2);
    #pragma unroll
    for (int n = 0; n < FN; ++n) {
        const int col = colbase + n * 16;
        const float bv = bias ? bias[col] : 0.f;
        #pragma unroll
        for (int m = 0; m < FM; ++m) {
            #pragma unroll
            for (int r = 0; r < 4; ++r) {
                const int row = rowbase + m * 16 + r;
                float v = acc[m][n][r] * scale + bv;
                if (relu) v = fmaxf(v, 0.f);
                if (Cw)  Cw[(size_t)row * Nc + col] = v;
                if (Cbw) Cbw[(size_t)row * Nc + col] = f2bf(v);
            }
        }
    }
}

// ---------------- MFMA flash rel-attention: split-j blocks, async K/R staging
// grid (32 = zt*2+js, 16 h, 2 b); 4 waves: iw = w&1 (q rows), jh = w>>1 (j half).
// Q from hproj cols [0,1024) (pre-scaled by 0.125); K/V per tile from:
//   j0 <  CM : kvmem  [B][CM][2048]  (k cols 0.., v cols 1024..)
//   j0 >= CM : hproj  [B][CS][3072]  (k cols 1024.., v cols 2048..)
// K/R in LDS linear [rows][64] with both-sides XOR chunk swizzle (chunk ^= row&7).
__global__ __launch_bounds__(256, 4)
void attn_kernel(const ushort* __restrict__ hproj, const ushort* __restrict__ kvmem,
                 const ushort* __restrict__ rbm,
                 const float* __restrict__ rwb, const float* __restrict__ rrb,
                 float* __restrict__ pw)
{
    // XCD swizzle over (x,y): same (h,b) zt-blocks stay on one XCD chunk
    const int id  = blockIdx.y * 32 + blockIdx.x;          // 512 per z
    const int swz = (id & 7) * 64 + (id >> 3);
    const int zt = (swz & 31) >> 1, js = swz & 1;
    const int hh = swz >> 5, bb = blockIdx.z;
    const int q0 = zt * 32;
    __shared__ __align__(16) ushort Ks[64 * 64];    // K rows, XOR-chunk layout
    __shared__ __align__(16) ushort Rs[96 * 64];    // R band rows, XOR-chunk layout
    __shared__ __align__(16) ushort Vt[80][72];     // V^T [d][j]; rows 64..79 = ones
    __shared__ __align__(16) ushort Pl[4][16][40];  // per-wave P [i][j_in32]
    __shared__ float mB[2][16], lB[2][16];
    const int tid = threadIdx.x;
    const int lane = tid & 63, w = tid >> 6;
    const int iw = w & 1, jh = w >> 1;
    const int g = lane >> 4, lo4 = lane & 15;

    // ones rows (never overwritten)
    for (int idx = tid; idx < 16 * 36; idx += 256)
        *(uint*)&Vt[64 + idx / 36][(idx % 36) * 2] = 0x3F803F80u;

    // Q fragments: q (bf16, pre-scaled) + biases (f32)
    short8 aqw[2], aqr[2];
    {
        const ushort* qrow = hproj + ((size_t)(bb * CS + q0 + iw * 16 + lo4)) * 3072 + hh * CDK;
        const float* bw = rwb + hh * CDK;
        const float* br = rrb + hh * CDK;
        #pragma unroll
        for (int c = 0; c < 2; ++c) {
            const int kb = c * 32 + g * 8;
            uint4 qv = *(const uint4*)&qrow[kb];
            const ushort* qe = (const ushort*)&qv;
            #pragma unroll
            for (int e = 0; e < 8; ++e) {
                float qf = bf2f(qe[e]);
                aqw[c][e] = (short)f2bf(qf + bw[kb + e]);
                aqr[c][e] = (short)f2bf(qf + br[kb + e]);
            }
        }
    }

    // region base pointers for this batch
    const ushort* kvmB = kvmem + (size_t)bb * CM * 2048;
    const ushort* hpjB = hproj + (size_t)bb * CS * 3072;
    const ushort* rb2  = rbm + hh * CDK;
    const int jp = tid & 31, c8v = tid >> 5;     // V staging roles

    float mr[4] = {-1e29f, -1e29f, -1e29f, -1e29f};
    f32x4 oacc[5];   // 4 d-frags + 1 ones-frag (row sums = l)
    #pragma unroll
    for (int n = 0; n < 5; ++n) oacc[n] = (f32x4){0.f, 0.f, 0.f, 0.f};

    const int nt   = (q0 + 31 + CM) / 64 + 1;
    const int half = nt >> 1;
    const int t0 = js ? half : 0;
    const int t1 = js ? nt : half;

    for (int tt = t0; tt < t1; ++tt) {
        const int j0 = tt * 64;
        const int bnd = j0 + 480 - q0;
        const int isMem = (j0 < CM);
        const ushort* kb2 = isMem ? (kvmB + hh * CDK) : (hpjB + 1024 + hh * CDK);
        const ushort* vb2 = isMem ? (kvmB + 1024 + hh * CDK) : (hpjB + 2048 + hh * CDK);
        const int rstr = isMem ? 2048 : 3072;
        const int jloc = isMem ? j0 : (j0 - CM);
        __syncthreads();                  // prev compute done with LDS
        // ---- K: async, 512 chunks; LDS[row][kc] = G[row][kc^(row&7)]
        #pragma unroll
        for (int c = 0; c < 2; ++c) {
            const int linw = (c * 4 + w) * 64;
            const int lin  = linw + lane;
            const int row = lin >> 3, kc = lin & 7;
            GLD16(kb2 + (size_t)(jloc + row) * rstr + ((kc ^ (row & 7)) * 8),
                  Ks + linw * 8);
        }
        // ---- R band: async, 768 chunks
        #pragma unroll
        for (int rep = 0; rep < 3; ++rep) {
            const int linw = (rep * 4 + w) * 64;
            const int lin  = linw + lane;
            const int row = lin >> 3, kc = lin & 7;
            int trel = bnd + row;
            trel = trel < 0 ? 0 : (trel > CT - 1 ? CT - 1 : trel);
            GLD16(rb2 + (size_t)trel * CD + ((kc ^ (row & 7)) * 8),
                  Rs + linw * 8);
        }
        // ---- V transposed (reg staging)
        {
            uint4 v0 = *(const uint4*)(vb2 + (size_t)(jloc + 2 * jp) * rstr + c8v * 8);
            uint4 v1 = *(const uint4*)(vb2 + (size_t)(jloc + 2 * jp + 1) * rstr + c8v * 8);
            const ushort* p0 = (const ushort*)&v0;
            const ushort* p1 = (const ushort*)&v1;
            #pragma unroll
            for (int e = 0; e < 8; ++e)
                *(uint*)&Vt[c8v * 8 + e][2 * jp] = (uint)p0[e] | ((uint)p1[e] << 16);
        }
        __syncthreads();                  // drains async loads + ds_writes

        // ---- content + rel scores
        f32x4 sa[2];
        sa[0] = (f32x4){0.f, 0.f, 0.f, 0.f};
        sa[1] = (f32x4){0.f, 0.f, 0.f, 0.f};
        f32x4 ra[3];
        #pragma unroll
        for (int mm = 0; mm < 3; ++mm) ra[mm] = (f32x4){0.f, 0.f, 0.f, 0.f};
        const int wb16 = jh * 32 - iw * 16 + 16;
        __builtin_amdgcn_s_setprio(1);
        #pragma unroll
        for (int c = 0; c < 2; ++c) {
            #pragma unroll
            for (int m16 = 0; m16 < 2; ++m16) {
                const int krow = jh * 32 + m16 * 16 + lo4;
                short8 bk = *(const short8*)&Ks[krow * 64 + ((((c << 2) + g) ^ (krow & 7)) << 3)];
                sa[m16] = __builtin_amdgcn_mfma_f32_16x16x32_bf16(aqw[c], bk, sa[m16], 0, 0, 0);
            }
            #pragma unroll
            for (int mm = 0; mm < 3; ++mm) {
                const int rrow = wb16 + mm * 16 + lo4;
                short8 brr = *(const short8*)&Rs[rrow * 64 + ((((c << 2) + g) ^ (rrow & 7)) << 3)];
                ra[mm] = __builtin_amdgcn_mfma_f32_16x16x32_bf16(aqr[c], brr, ra[mm], 0, 0, 0);
            }
        }
        __builtin_amdgcn_s_setprio(0);

        // ---- rel gather + mask + online softmax (max only; sum via ones-MFMA)
        #pragma unroll
        for (int r = 0; r < 4; ++r) {
            const int il = 4 * g + r;
            const int dlo = lo4 + 15 - il;              // [0,30]
            const int srcl = (lane & 48) | (dlo & 15);
            const int hi = dlo >> 4;
            float va = __shfl(ra[0][r], srcl);
            float vb = __shfl(ra[1][r], srcl);
            float vc = __shfl(ra[2][r], srcl);
            const float rel0 = hi ? vb : va;
            const float rel1 = hi ? vc : vb;
            const int ig = q0 + iw * 16 + il;
            const int jbase = j0 + jh * 32 + lo4;
            float s0 = (jbase      <= ig + CM) ? (sa[0][r] + rel0) : -1e30f;
            float s1 = (jbase + 16 <= ig + CM) ? (sa[1][r] + rel1) : -1e30f;
            float tm = fmaxf(s0, s1);
            #pragma unroll
            for (int off = 1; off < 16; off <<= 1) tm = fmaxf(tm, __shfl_xor(tm, off));
            const float mn = fmaxf(mr[r], tm);
            const float scl = __expf(mr[r] - mn);
            mr[r] = mn;
            Pl[w][il][lo4]      = f2bf(__expf(s0 - mn));
            Pl[w][il][16 + lo4] = f2bf(__expf(s1 - mn));
            #pragma unroll
            for (int n = 0; n < 5; ++n) oacc[n][r] *= scl;
        }

        // ---- PV (+ones): O += P·V, l += P·1
        __builtin_amdgcn_s_setprio(1);
        {
            short8 pa = *(const short8*)&Pl[w][lo4][g * 8];
            #pragma unroll
            for (int n = 0; n < 4; ++n) {
                short8 vb = *(const short8*)&Vt[n * 16 + lo4][jh * 32 + g * 8];
                oacc[n] = __builtin_amdgcn_mfma_f32_16x16x32_bf16(pa, vb, oacc[n], 0, 0, 0);
            }
            short8 vo = *(const short8*)&Vt[64 + lo4][jh * 32 + g * 8];
            oacc[4] = __builtin_amdgcn_mfma_f32_16x16x32_bf16(pa, vo, oacc[4], 0, 0, 0);
        }
        __builtin_amdgcn_s_setprio(0);
    }

    // ---- merge j-halves in-block, write partial (O,m,l) to pw
    __syncthreads();
    float* oTmp = (float*)&Rs[0];          // 8 KB of the 12 KB Rs region
    if (jh == 1) {
        #pragma unroll
        for (int r = 0; r < 4; ++r) {
            const int il = 4 * g + r;
            #pragma unroll
            for (int n = 0; n < 4; ++n)
                oTmp[((iw * 16 + il) << 6) + n * 16 + lo4] = oacc[n][r];
            if (lo4 == 0) { mB[iw][il] = mr[r]; lB[iw][il] = oacc[4][r]; }
        }
    }
    __syncthreads();
    if (jh == 0) {
        float* pwp = pw + ((size_t)(((bb * CH + hh) * 16 + zt) * 2 + js)) * 2112;
        #pragma unroll
        for (int r = 0; r < 4; ++r) {
            const int il = 4 * g + r;
            const int row = iw * 16 + il;
            const float mBv = mB[iw][il], lBv = lB[iw][il];
            const float ms = fmaxf(mr[r], mBv);
            const float fA = __expf(mr[r] - ms);
            const float fB = __expf(mBv - ms);
            const float lt = oacc[4][r] * fA + lBv * fB;
            #pragma unroll
            for (int n = 0; n < 4; ++n)
                pwp[(row << 6) + n * 16 + lo4] =
                    oacc[n][r] * fA + oTmp[(row << 6) + n * 16 + lo4] * fB;
            if (lo4 == 0) { pwp[2048 + row] = ms; pwp[2048 + 32 + row] = lt; }
        }
    }
}

// ---------------- merge the two split-j partials -> bf16 output
__global__ __launch_bounds__(256)
void attn_merge(const float* __restrict__ pw, ushort* __restrict__ outm) {
    const int zt = blockIdx.x, hh = blockIdx.y, bb = blockIdx.z;
    const int tid = threadIdx.x;
    const int row = tid >> 3, c8 = tid & 7;
    const float* pA = pw + ((size_t)(((bb * CH + hh) * 16 + zt) * 2 + 0)) * 2112;
    const float* pB = pA + 2112;
    const float mA = pA[2048 + row], lA = pA[2048 + 32 + row];
    const float mBv = pB[2048 + row], lBv = pB[2048 + 32 + row];
    const float ms = fmaxf(mA, mBv);
    const float fA = __expf(mA - ms);
    const float fB = __expf(mBv - ms);
    const float invl = 1.0f / (lA * fA + lBv * fB);
    float4 a0 = *(const float4*)&pA[(row << 6) + c8 * 8];
    float4 a1 = *(const float4*)&pA[(row << 6) + c8 * 8 + 4];
    float4 b0 = *(const float4*)&pB[(row << 6) + c8 * 8];
    float4 b1 = *(const float4*)&pB[(row << 6) + c8 * 8 + 4];
    union { ushort us[8]; uint4 q; } pk;
    pk.us[0] = f2bf((a0.x * fA + b0.x * fB) * invl);
    pk.us[1] = f2bf((a0.y * fA + b0.y * fB) * invl);
    pk.us[2] = f2bf((a0.z * fA + b0.z * fB) * invl);
    pk.us[3] = f2bf((a0.w * fA + b0.w * fB) * invl);
    pk.us[4] = f2bf((a1.x * fA + b1.x * fB) * invl);
    pk.us[5] = f2bf((a1.y * fA + b1.y * fB) * invl);
    pk.us[6] = f2bf((a1.z * fA + b1.z * fB) * invl);
    pk.us[7] = f2bf((a1.w * fA + b1.w * fB) * invl);
    *(uint4*)&outm[((size_t)(bb * CS + zt * 32 + row)) * CD + hh * CDK + c8 * 8] = pk.q;
}

// ---------------- residual + 2 partials (+row bias) + layernorm, dual output
__global__ __launch_bounds__(256)
void ln_kernel(const float* __restrict__ a, const float* __restrict__ p0,
               const float* __restrict__ p1, const float* __restrict__ bias,
               const float* __restrict__ g, const float* __restrict__ beta,
               float* __restrict__ out, ushort* __restrict__ outbf)
{
    const int row = blockIdx.x;
    const int tid = threadIdx.x;
    const size_t base = (size_t)row * CD;
    float4 xa = *(const float4*)&a[base + tid * 4];
    float4 x0v = *(const float4*)&p0[base + tid * 4];
    float4 x1v = *(const float4*)&p1[base + tid * 4];
    float4 bb = bias ? *(const float4*)&bias[tid * 4] : make_float4(0.f, 0.f, 0.f, 0.f);
    float x0 = xa.x + x0v.x + x1v.x + bb.x;
    float x1 = xa.y + x0v.y + x1v.y + bb.y;
    float x2 = xa.z + x0v.z + x1v.z + bb.z;
    float x3 = xa.w + x0v.w + x1v.w + bb.w;
    float sum = x0 + x1 + x2 + x3;
    float sq  = x0 * x0 + x1 * x1 + x2 * x2 + x3 * x3;
    #pragma unroll
    for (int off = 1; off < 64; off <<= 1) {
        sum += __shfl_xor(sum, off);
        sq  += __shfl_xor(sq, off);
    }
    __shared__ float ssum[4], ssq[4];
    const int wid = tid >> 6;
    if ((tid & 63) == 0) { ssum[wid] = sum; ssq[wid] = sq; }
    __syncthreads();
    sum = ssum[0] + ssum[1] + ssum[2] + ssum[3];
    sq  = ssq[0] + ssq[1] + ssq[2] + ssq[3];
    const float mean = sum * (1.0f / CD);
    const float var  = sq * (1.0f / CD) - mean * mean;
    const float rstd = rsqrtf(var + 1e-5f);
    float4 gv = *(const float4*)&g[tid * 4];
    float4 bv = *(const float4*)&beta[tid * 4];
    float4 r;
    r.x = (x0 - mean) * rstd * gv.x + bv.x;
    r.y = (x1 - mean) * rstd * gv.y + bv.y;
    r.z = (x2 - mean) * rstd * gv.z + bv.z;
    r.w = (x3 - mean) * rstd * gv.w + bv.w;
    *(float4*)&out[base + tid * 4] = r;
    if (outbf) {
        union { ushort us[4]; uint2 q; } pk;
        pk.us[0] = f2bf(r.x); pk.us[1] = f2bf(r.y); pk.us[2] = f2bf(r.z); pk.us[3] = f2bf(r.w);
        *(uint2*)&outbf[base + tid * 4] = pk.q;
    }
}

extern "C" void kernel_launch(void* const* d_in, const int* in_sizes, int n_in,
                              void* d_out, int out_size, void* d_ws, size_t ws_size,
                              hipStream_t stream) {
    const float* x    = (const float*)d_in[0];
    const float* memL = (const float*)d_in[1];
    const float* Wq   = (const float*)d_in[2];
    const float* Wk   = (const float*)d_in[3];
    const float* Wv   = (const float*)d_in[4];
    const float* Wr   = (const float*)d_in[5];
    const float* Wo   = (const float*)d_in[6];
    const float* rwb  = (const float*)d_in[7];
    const float* rrb  = (const float*)d_in[8];
    const float* ln1g = (const float*)d_in[9];
    const float* ln1b = (const float*)d_in[10];
    const float* ln2g = (const float*)d_in[11];
    const float* ln2b = (const float*)d_in[12];
    const float* W1   = (const float*)d_in[13];
    const float* b1   = (const float*)d_in[14];
    const float* W2   = (const float*)d_in[15];
    const float* b2   = (const float*)d_in[16];

    const size_t MEG = 1048576;
    float* h      = (float*)d_ws;                 // 1M f32
    float* p0     = h + MEG;                      // 1M f32
    float* p1     = p0 + MEG;                     // 1M f32
    float* pw     = p1 + MEG;                     // 1024 x 2112 f32
    float* pg     = pw + 1024 * 2112;             // 8M f32 (2 x 4M split-K partials)
    ushort* hbf   = (ushort*)(pg + 8 * MEG);      // 1M us  (contiguous h, bf16)
    ushort* membf = hbf + MEG;                    // 4M us  [L][B*M][D]
    ushort* kvmem = membf + 4 * MEG;              // 8M us  [L][B*M][2048] k|v
    ushort* hproj = kvmem + 8 * MEG;              // 3M us  [B*S][3072] q|k|v
    ushort* attbf = hproj + 3 * MEG;              // 1M us
    ushort* ff1bf = attbf + MEG;                  // 4M us
    ushort* posbf = ff1bf + 4 * MEG;              // 1M us
    ushort* r_all = posbf + MEG;                  // 4M us  [L][T][D]
    ushort* wqkvT = r_all + 4 * MEG;              // 12M us [L][3D][D]
    ushort* wrT   = wqkvT + 12 * MEG;             // 4M us
    ushort* woT   = wrT + 4 * MEG;                // 4M us
    ushort* w1T   = woT + 4 * MEG;                // 16M us [L][FF][D]
    ushort* w2T   = w1T + 16 * MEG;               // 16M us [L][D][FF]
    // total ~212 MB (ws ~268 MB)

    const size_t WD = (size_t)CD * CD;

    // ---------- loop-invariant preamble ----------
    pos_kernel<<<(CT * (CD / 2)) / 256, 256, 0, stream>>>(posbf);
    cvt_bf16_kernel<<<(CL * CB * CM * CD / 8) / 256, 256, 0, stream>>>(
        memL, membf, CL * CB * CM * CD / 8);
    cvt_bf16_kernel<<<(CB * CS * CD / 8) / 256, 256, 0, stream>>>(
        x, hbf, CB * CS * CD / 8);
    transpose_w5<<<dim3(16, 16, 5 * CL), 256, 0, stream>>>(Wq, Wk, Wv, Wr, Wo, wqkvT, wrT, woT);
    transpose_cvt<<<dim3(64, 16, CL), 256, 0, stream>>>(W1, w1T, CD, CFF, 4 * WD, 4 * WD);
    transpose_cvt<<<dim3(16, 64, CL), 256, 0, stream>>>(W2, w2T, CFF, CD, 4 * WD, 4 * WD);
    // r_all[l] = pos @ Wr_l  (batched over z = layer); chunks 4x8
    gemm_bf16<64, 64><<<dim3(16, 16, CL), 256, 0, stream>>>(
        posbf, wrT, nullptr, r_all, CD, CD, CD, 4, 8, 0, WD, (size_t)CT * CD,
        nullptr, 1.0f, 0);
    // kvmem[l] = mem_l @ [Wk|Wv]_l  (batched over z = layer); chunks 4x8
    gemm_bf16<64, 128><<<dim3(16, 16, CL), 256, 0, stream>>>(
        membf, wqkvT + WD, nullptr, kvmem,
        2 * CD, CD, CD, 4, 8, MEG, 3 * WD, 2 * MEG, nullptr, 1.0f, 0);

    // ---------- layer loop ----------
    for (int l = 0; l < CL; ++l) {
        const float* hin = (l == 0) ? x : h;

        // hproj = h @ [Wq|Wk|Wv]_l  split-K=2 -> f32 partials -> combine -> bf16
        gemm_bf16<64, 128><<<dim3(24, 16, 2), 256, 0, stream>>>(
            hbf, wqkvT + (size_t)l * 3 * WD, pg, nullptr,
            3 * CD, CD / 2, CD, 6, 8, CD / 2, CD / 2, 4 * MEG, nullptr, 1.0f, 0);
        combine_bf16<<<(CB * CS * 3 * CD / 8) / 256, 256, 0, stream>>>(
            pg, pg + 4 * MEG, nullptr, 3 * CD / 8, hproj, CB * CS * 3 * CD / 8, 0);

        // fused relative attention (split-j) -> partials -> merge -> bf16
        attn_kernel<<<dim3(2 * CS / 32, CH, CB), 256, 0, stream>>>(
            hproj, kvmem + (size_t)l * 2 * MEG, r_all + (size_t)l * CT * CD,
            rwb + (size_t)l * CH * CDK, rrb + (size_t)l * CH * CDK, pw);
        attn_merge<<<dim3(CS / 32, CH, CB), 256, 0, stream>>>(pw, attbf);

        // merge linear (split-K=2 -> p0,p1) + LN1; chunks 4x8
        gemm_bf16<64, 64><<<dim3(16, 16, 2), 256, 0, stream>>>(
            attbf, woT + (size_t)l * WD, p0, nullptr,
            CD, CD / 2, CD, 4, 8, CD / 2, CD / 2, MEG, nullptr, 1.0f, 0);
        ln_kernel<<<CB * CS, 256, 0, stream>>>(
            hin, p0, p1, nullptr, ln1g + (size_t)l * CD, ln1b + (size_t)l * CD, h, hbf);

        // FF1: h@W1 split-K=2 -> f32 partials -> combine(+b1, relu) -> bf16
        gemm_bf16<64, 128><<<dim3(32, 16, 2), 256, 0, stream>>>(
            hbf, w1T + (size_t)l * 4 * WD, pg, nullptr,
            CFF, CD / 2, CD, 8, 8, CD / 2, CD / 2, 4 * MEG, nullptr, 1.0f, 0);
        combine_bf16<<<(CB * CS * CFF / 8) / 256, 256, 0, stream>>>(
            pg, pg + 4 * MEG, b1 + (size_t)l * CFF, CFF / 8, ff1bf, CB * CS * CFF / 8, 1);

        // FF2: ff1@W2 split-K=2 (chunks 4x8) + LN2(h + ff + b2)
        gemm_bf16<64, 64><<<dim3(16, 16, 2), 256, 0, stream>>>(
            ff1bf, w2T + (size_t)l * 4 * WD, p0, nullptr,
            CD, CFF / 2, CFF, 4, 8, CFF / 2, CFF / 2, MEG, nullptr, 1.0f, 0);
        ln_kernel<<<CB * CS, 256, 0, stream>>>(
            h, p0, p1, b2 + (size_t)l * CD, ln2g + (size_t)l * CD, ln2b + (size_t)l * CD,
            (l == CL - 1) ? (float*)d_out : h,
            (l == CL - 1) ? nullptr : hbf);
    }
}

// Round 17
// 559.964 us; speedup vs baseline: 1.1044x; 1.1044x over previous
//
#include <hip/hip_runtime.h>
#include <math.h>

// Transformer-XL tower. bf16 MFMA GEMMs (BK=64 ring pipeline auto-sized to 48KB LDS,
// counted vmcnt + T2 swizzle + 2D-chunked XCD mapping, split-K, z-batched)
// + MFMA flash attention (split-j + merge, async K/R staging).
// == round-14 configuration (measured best: 563 us) ==
// L=4, B=2, S=512, M=512, D=1024, H=16, DK=64, FF=4096, T=S+M=1024
#define CB  2
#define CS  512
#define CM  512
#define CD  1024
#define CH  16
#define CDK 64
#define CFF 4096
#define CL  4
#define CT  1024

using short8 = __attribute__((ext_vector_type(8))) short;
using f32x4  = __attribute__((ext_vector_type(4))) float;

__device__ __forceinline__ ushort f2bf(float x) {
    union { float f; unsigned int u; } c; c.f = x;
    unsigned int u = c.u + 0x7FFFu + ((c.u >> 16) & 1u);
    return (ushort)(u >> 16);
}
__device__ __forceinline__ float bf2f(ushort h) {
    union { unsigned int u; float f; } c; c.u = ((unsigned int)h) << 16;
    return c.f;
}

// async global->LDS, 16B per lane; dest = wave-uniform base + lane*16
#define GLD16(gsrc, ldst) \
    __builtin_amdgcn_global_load_lds((const __attribute__((address_space(1))) void*)(gsrc), \
                                     (__attribute__((address_space(3))) void*)(ldst), 16, 0, 0)

// ---------------- positional encodings -> bf16 [T][D]
__global__ void pos_kernel(ushort* __restrict__ pos) {
    int idx = blockIdx.x * blockDim.x + threadIdx.x;   // T * D/2
    if (idx >= CT * (CD / 2)) return;
    int i = idx % (CD / 2);
    int t = idx / (CD / 2);
    float p = (float)(CT - 1 - t);
    float inv = __expf(-(float)i * (9.210340371976184f / 512.0f));
    float ang = p * inv;
    pos[(size_t)t * CD + i]          = f2bf(sinf(ang));
    pos[(size_t)t * CD + i + CD / 2] = f2bf(cosf(ang));
}

// ---------------- elementwise f32 -> bf16 (n8 = count/8)
__global__ void cvt_bf16_kernel(const float* __restrict__ in, ushort* __restrict__ out, int n8) {
    int i = blockIdx.x * blockDim.x + threadIdx.x;
    if (i >= n8) return;
    float4 a = ((const float4*)in)[i * 2];
    float4 c = ((const float4*)in)[i * 2 + 1];
    union { ushort us[8]; uint4 q; } pk;
    pk.us[0] = f2bf(a.x); pk.us[1] = f2bf(a.y); pk.us[2] = f2bf(a.z); pk.us[3] = f2bf(a.w);
    pk.us[4] = f2bf(c.x); pk.us[5] = f2bf(c.y); pk.us[6] = f2bf(c.z); pk.us[7] = f2bf(c.w);
    ((uint4*)out)[i] = pk.q;
}

// ---------------- transpose+convert the 5 DxD weight families in one launch
// z = wi*CL + l, wi in {0:Wq(*0.125),1:Wk,2:Wv,3:Wr,4:Wo}
__global__ __launch_bounds__(256)
void transpose_w5(const float* __restrict__ Wq, const float* __restrict__ Wk,
                  const float* __restrict__ Wv, const float* __restrict__ Wr,
                  const float* __restrict__ Wo,
                  ushort* __restrict__ wqkvT, ushort* __restrict__ wrT,
                  ushort* __restrict__ woT) {
    const size_t WD = (size_t)CD * CD;
    const int wi = blockIdx.z / CL, l = blockIdx.z % CL;
    const float* in;
    ushort* o;
    float sc = 1.0f;
    switch (wi) {
        case 0: in = Wq + l * WD; o = wqkvT + (size_t)l * 3 * WD; sc = 0.125f; break;
        case 1: in = Wk + l * WD; o = wqkvT + (size_t)l * 3 * WD + WD; break;
        case 2: in = Wv + l * WD; o = wqkvT + (size_t)l * 3 * WD + 2 * WD; break;
        case 3: in = Wr + l * WD; o = wrT + (size_t)l * WD; break;
        default: in = Wo + l * WD; o = woT + (size_t)l * WD; break;
    }
    __shared__ __align__(16) float t[64][68];
    const int n0 = blockIdx.x * 64, k0 = blockIdx.y * 64;
    const int tid = threadIdx.x;
    #pragma unroll
    for (int rep = 0; rep < 4; ++rep) {
        int lin = rep * 256 + tid;
        int r = lin >> 4, c4 = lin & 15;
        float4 v = *(const float4*)&in[(size_t)(k0 + r) * CD + n0 + c4 * 4];
        *(float4*)&t[r][c4 * 4] = v;
    }
    __syncthreads();
    #pragma unroll
    for (int rep = 0; rep < 2; ++rep) {
        int lin = rep * 256 + tid;
        int n = lin >> 3, kc = lin & 7;
        union { ushort us[8]; uint4 q; } pk;
        #pragma unroll
        for (int j = 0; j < 8; ++j) pk.us[j] = f2bf(t[kc * 8 + j][n] * sc);
        *(uint4*)&o[(size_t)(n0 + n) * CD + k0 + kc * 8] = pk.q;
    }
}

// ---------------- transpose+convert, z-batched (for W1/W2)
__global__ __launch_bounds__(256)
void transpose_cvt(const float* __restrict__ inb, ushort* __restrict__ outb,
                   int Kd, int Nc, size_t inz, size_t outz) {
    const float* in = inb + (size_t)blockIdx.z * inz;
    ushort* o = outb + (size_t)blockIdx.z * outz;
    __shared__ __align__(16) float t[64][68];
    const int n0 = blockIdx.x * 64, k0 = blockIdx.y * 64;
    const int tid = threadIdx.x;
    #pragma unroll
    for (int rep = 0; rep < 4; ++rep) {
        int lin = rep * 256 + tid;
        int r = lin >> 4, c4 = lin & 15;
        float4 v = *(const float4*)&in[(size_t)(k0 + r) * Nc + n0 + c4 * 4];
        *(float4*)&t[r][c4 * 4] = v;
    }
    __syncthreads();
    #pragma unroll
    for (int rep = 0; rep < 2; ++rep) {
        int lin = rep * 256 + tid;
        int n = lin >> 3, kc = lin & 7;
        union { ushort us[8]; uint4 q; } pk;
        #pragma unroll
        for (int j = 0; j < 8; ++j) pk.us[j] = f2bf(t[kc * 8 + j][n]);
        *(uint4*)&o[(size_t)(n0 + n) * Kd + k0 + kc * 8] = pk.q;
    }
}

// ---------------- bf16 MFMA GEMM: C[M,N] = A[M,K(lda)] @ Bt[N,K(lda)]^T
// BMxBN tile, BK=64, 4 waves (2x2); ring pipeline with counted vmcnt, ring depth
// chosen so LDS <= 48KB (3 blocks/CU). T2 XOR swizzle, 2D-chunked XCD mapping.
// blockIdx.z: offsets az/bz/cz (split-K or batch).
template<int BM, int BN>
__global__ __launch_bounds__(256)
void gemm_bf16(const ushort* __restrict__ A, const ushort* __restrict__ Bt,
               float* __restrict__ Cf, ushort* __restrict__ Cbf,
               int Nc, int Kd, int lda, int cw, int ch,
               size_t az, size_t bz, size_t cz,
               const float* __restrict__ bias, float scale, int relu)
{
    constexpr int FM = BM / 32, FN = BN / 32;
    constexpr int LPW = BM / 32 + BN / 32;        // global_load_lds per wave per step
    constexpr int STEPB = (BM + BN) * 64 * 2;     // LDS bytes per K-step
    constexpr int RING = (3 * STEPB <= 49152) ? 3 : 2;
    __shared__ __align__(16) ushort As[RING][BM * 64];
    __shared__ __align__(16) ushort Bs[RING][BN * 64];
    const int tid  = threadIdx.x;
    const int lane = tid & 63, w = tid >> 6;
    const int wr = w >> 1, wc = w & 1;
    const int lo4 = lane & 15, g = lane >> 4;
    // chunked XCD mapping (HW round-robins id%8 across XCDs)
    const int id  = blockIdx.y * gridDim.x + blockIdx.x;
    const int e = id & 7, q = id >> 3;
    const int ncx = gridDim.x / cw;
    const int col0 = ((e % ncx) * cw + q % cw) * BN;
    const int row0 = ((e / ncx) * ch + q / cw) * BM;
    const int zz = blockIdx.z;
    const ushort* Ab = A  + (size_t)row0 * lda + (size_t)zz * az;
    const ushort* Bb = Bt + (size_t)col0 * lda + (size_t)zz * bz;
    f32x4 acc[FM][FN];
    #pragma unroll
    for (int m = 0; m < FM; ++m)
        #pragma unroll
        for (int n = 0; n < FN; ++n) acc[m][n] = (f32x4){0.f, 0.f, 0.f, 0.f};

#define GSTAGE(buf, kk) do {                                                          \
        _Pragma("unroll")                                                             \
        for (int c = 0; c < BM / 32; ++c) {                                           \
            const int linw = (c * 4 + w) * 64;                                        \
            const int lin  = linw + lane;                                             \
            GLD16(Ab + (size_t)(lin >> 3) * lda + (kk) + ((lin ^ (lin >> 3)) & 7) * 8, \
                  &As[buf][linw * 8]);                                                \
        }                                                                             \
        _Pragma("unroll")                                                             \
        for (int c = 0; c < BN / 32; ++c) {                                           \
            const int linw = (c * 4 + w) * 64;                                        \
            const int lin  = linw + lane;                                             \
            GLD16(Bb + (size_t)(lin >> 3) * lda + (kk) + ((lin ^ (lin >> 3)) & 7) * 8, \
                  &Bs[buf][linw * 8]);                                                \
        }                                                                             \
    } while (0)

    const int nsteps = Kd / 64;   // always >= 8 in this kernel's uses
    GSTAGE(0, 0);
    GSTAGE(1, 64);
    if constexpr (RING == 3) GSTAGE(2, 128);
    int buf = 0;
    for (int s = 0; s < nsteps; ++s) {
        // B1: this step's loads landed (own outstanding <= RING-1 steps)
        asm volatile("s_waitcnt vmcnt(%0)" :: "n"((RING - 1) * LPW) : "memory");
        __builtin_amdgcn_s_barrier();
        __builtin_amdgcn_sched_barrier(0);
        short8 af[2][FM], bfr[2][FN];
        #pragma unroll
        for (int h2 = 0; h2 < 2; ++h2) {
            #pragma unroll
            for (int m = 0; m < FM; ++m) {
                const int ar = wr * (BM / 2) + m * 16 + lo4;
                af[h2][m] = *(const short8*)&As[buf][ar * 64 + ((((h2 << 2) + g) ^ (ar & 7)) << 3)];
            }
            #pragma unroll
            for (int n = 0; n < FN; ++n) {
                const int br = wc * (BN / 2) + n * 16 + lo4;
                bfr[h2][n] = *(const short8*)&Bs[buf][br * 64 + ((((h2 << 2) + g) ^ (br & 7)) << 3)];
            }
        }
        asm volatile("s_waitcnt lgkmcnt(0)" ::: "memory");
        __builtin_amdgcn_sched_barrier(0);
        __builtin_amdgcn_s_barrier();          // B2: all waves done reading buf
        if (s + RING < nsteps) GSTAGE(buf, (s + RING) * 64);   // refill freed buffer
        __builtin_amdgcn_s_setprio(1);
        #pragma unroll
        for (int h2 = 0; h2 < 2; ++h2)
            #pragma unroll
            for (int m = 0; m < FM; ++m)
                #pragma unroll
                for (int n = 0; n < FN; ++n)
                    acc[m][n] = __builtin_amdgcn_mfma_f32_16x16x32_bf16(
                        af[h2][m], bfr[h2][n], acc[m][n], 0, 0, 0);
        __builtin_amdgcn_s_setprio(0);
        buf = (buf == RING - 1) ? 0 : buf + 1;
    }
#undef GSTAGE

    float*  Cw  = Cf  ? Cf  + (size_t)zz * cz : nullptr;
    ushort* Cbw = Cbf ? Cbf + (size_t)zz * cz : nullptr;
    const int colbase = col0 + wc * (BN / 2) + lo4;
    const int rowbase = row0 + wr * (BM / 2) + (g << 2);
    #pragma unroll
    for (int n = 0; n < FN; ++n) {
        const int col = colbase + n * 16;
        const float bv = bias ? bias[col] : 0.f;
        #pragma unroll
        for (int m = 0; m < FM; ++m) {
            #pragma unroll
            for (int r = 0; r < 4; ++r) {
                const int row = rowbase + m * 16 + r;
                float v = acc[m][n][r] * scale + bv;
                if (relu) v = fmaxf(v, 0.f);
                if (Cw)  Cw[(size_t)row * Nc + col] = v;
                if (Cbw) Cbw[(size_t)row * Nc + col] = f2bf(v);
            }
        }
    }
}

// ---------------- MFMA flash rel-attention: split-j blocks, async K/R staging
// grid (32 = zt*2+js, 16 h, 2 b); 4 waves: iw = w&1 (q rows), jh = w>>1 (j half).
// Q from hproj cols [0,1024) (pre-scaled by 0.125); K/V per tile from:
//   j0 <  CM : kvmem  [B][CM][2048]  (k cols 0.., v cols 1024..)
//   j0 >= CM : hproj  [B][CS][3072]  (k cols 1024.., v cols 2048..)
// K/R in LDS linear [rows][64] with both-sides XOR chunk swizzle (chunk ^= row&7).
__global__ __launch_bounds__(256, 4)
void attn_kernel(const ushort* __restrict__ hproj, const ushort* __restrict__ kvmem,
                 const ushort* __restrict__ rbm,
                 const float* __restrict__ rwb, const float* __restrict__ rrb,
                 float* __restrict__ pw)
{
    // XCD swizzle over (x,y): same (h,b) zt-blocks stay on one XCD chunk
    const int id  = blockIdx.y * 32 + blockIdx.x;          // 512 per z
    const int swz = (id & 7) * 64 + (id >> 3);
    const int zt = (swz & 31) >> 1, js = swz & 1;
    const int hh = swz >> 5, bb = blockIdx.z;
    const int q0 = zt * 32;
    __shared__ __align__(16) ushort Ks[64 * 64];    // K rows, XOR-chunk layout
    __shared__ __align__(16) ushort Rs[96 * 64];    // R band rows, XOR-chunk layout
    __shared__ __align__(16) ushort Vt[80][72];     // V^T [d][j]; rows 64..79 = ones
    __shared__ __align__(16) ushort Pl[4][16][40];  // per-wave P [i][j_in32]
    __shared__ float mB[2][16], lB[2][16];
    const int tid = threadIdx.x;
    const int lane = tid & 63, w = tid >> 6;
    const int iw = w & 1, jh = w >> 1;
    const int g = lane >> 4, lo4 = lane & 15;

    // ones rows (never overwritten)
    for (int idx = tid; idx < 16 * 36; idx += 256)
        *(uint*)&Vt[64 + idx / 36][(idx % 36) * 2] = 0x3F803F80u;

    // Q fragments: q (bf16, pre-scaled) + biases (f32)
    short8 aqw[2], aqr[2];
    {
        const ushort* qrow = hproj + ((size_t)(bb * CS + q0 + iw * 16 + lo4)) * 3072 + hh * CDK;
        const float* bw = rwb + hh * CDK;
        const float* br = rrb + hh * CDK;
        #pragma unroll
        for (int c = 0; c < 2; ++c) {
            const int kb = c * 32 + g * 8;
            uint4 qv = *(const uint4*)&qrow[kb];
            const ushort* qe = (const ushort*)&qv;
            #pragma unroll
            for (int e = 0; e < 8; ++e) {
                float qf = bf2f(qe[e]);
                aqw[c][e] = (short)f2bf(qf + bw[kb + e]);
                aqr[c][e] = (short)f2bf(qf + br[kb + e]);
            }
        }
    }

    // region base pointers for this batch
    const ushort* kvmB = kvmem + (size_t)bb * CM * 2048;
    const ushort* hpjB = hproj + (size_t)bb * CS * 3072;
    const ushort* rb2  = rbm + hh * CDK;
    const int jp = tid & 31, c8v = tid >> 5;     // V staging roles

    float mr[4] = {-1e29f, -1e29f, -1e29f, -1e29f};
    f32x4 oacc[5];   // 4 d-frags + 1 ones-frag (row sums = l)
    #pragma unroll
    for (int n = 0; n < 5; ++n) oacc[n] = (f32x4){0.f, 0.f, 0.f, 0.f};

    const int nt   = (q0 + 31 + CM) / 64 + 1;
    const int half = nt >> 1;
    const int t0 = js ? half : 0;
    const int t1 = js ? nt : half;

    for (int tt = t0; tt < t1; ++tt) {
        const int j0 = tt * 64;
        const int bnd = j0 + 480 - q0;
        const int isMem = (j0 < CM);
        const ushort* kb2 = isMem ? (kvmB + hh * CDK) : (hpjB + 1024 + hh * CDK);
        const ushort* vb2 = isMem ? (kvmB + 1024 + hh * CDK) : (hpjB + 2048 + hh * CDK);
        const int rstr = isMem ? 2048 : 3072;
        const int jloc = isMem ? j0 : (j0 - CM);
        __syncthreads();                  // prev compute done with LDS
        // ---- K: async, 512 chunks; LDS[row][kc] = G[row][kc^(row&7)]
        #pragma unroll
        for (int c = 0; c < 2; ++c) {
            const int linw = (c * 4 + w) * 64;
            const int lin  = linw + lane;
            const int row = lin >> 3, kc = lin & 7;
            GLD16(kb2 + (size_t)(jloc + row) * rstr + ((kc ^ (row & 7)) * 8),
                  Ks + linw * 8);
        }
        // ---- R band: async, 768 chunks
        #pragma unroll
        for (int rep = 0; rep < 3; ++rep) {
            const int linw = (rep * 4 + w) * 64;
            const int lin  = linw + lane;
            const int row = lin >> 3, kc = lin & 7;
            int trel = bnd + row;
            trel = trel < 0 ? 0 : (trel > CT - 1 ? CT - 1 : trel);
            GLD16(rb2 + (size_t)trel * CD + ((kc ^ (row & 7)) * 8),
                  Rs + linw * 8);
        }
        // ---- V transposed (reg staging)
        {
            uint4 v0 = *(const uint4*)(vb2 + (size_t)(jloc + 2 * jp) * rstr + c8v * 8);
            uint4 v1 = *(const uint4*)(vb2 + (size_t)(jloc + 2 * jp + 1) * rstr + c8v * 8);
            const ushort* p0 = (const ushort*)&v0;
            const ushort* p1 = (const ushort*)&v1;
            #pragma unroll
            for (int e = 0; e < 8; ++e)
                *(uint*)&Vt[c8v * 8 + e][2 * jp] = (uint)p0[e] | ((uint)p1[e] << 16);
        }
        __syncthreads();                  // drains async loads + ds_writes

        // ---- content + rel scores
        f32x4 sa[2];
        sa[0] = (f32x4){0.f, 0.f, 0.f, 0.f};
        sa[1] = (f32x4){0.f, 0.f, 0.f, 0.f};
        f32x4 ra[3];
        #pragma unroll
        for (int mm = 0; mm < 3; ++mm) ra[mm] = (f32x4){0.f, 0.f, 0.f, 0.f};
        const int wb16 = jh * 32 - iw * 16 + 16;
        __builtin_amdgcn_s_setprio(1);
        #pragma unroll
        for (int c = 0; c < 2; ++c) {
            #pragma unroll
            for (int m16 = 0; m16 < 2; ++m16) {
                const int krow = jh * 32 + m16 * 16 + lo4;
                short8 bk = *(const short8*)&Ks[krow * 64 + ((((c << 2) + g) ^ (krow & 7)) << 3)];
                sa[m16] = __builtin_amdgcn_mfma_f32_16x16x32_bf16(aqw[c], bk, sa[m16], 0, 0, 0);
            }
            #pragma unroll
            for (int mm = 0; mm < 3; ++mm) {
                const int rrow = wb16 + mm * 16 + lo4;
                short8 brr = *(const short8*)&Rs[rrow * 64 + ((((c << 2) + g) ^ (rrow & 7)) << 3)];
                ra[mm] = __builtin_amdgcn_mfma_f32_16x16x32_bf16(aqr[c], brr, ra[mm], 0, 0, 0);
            }
        }
        __builtin_amdgcn_s_setprio(0);

        // ---- rel gather + mask + online softmax (max only; sum via ones-MFMA)
        #pragma unroll
        for (int r = 0; r < 4; ++r) {
            const int il = 4 * g + r;
            const int dlo = lo4 + 15 - il;              // [0,30]
            const int srcl = (lane & 48) | (dlo & 15);
            const int hi = dlo >> 4;
            float va = __shfl(ra[0][r], srcl);
            float vb = __shfl(ra[1][r], srcl);
            float vc = __shfl(ra[2][r], srcl);
            const float rel0 = hi ? vb : va;
            const float rel1 = hi ? vc : vb;
            const int ig = q0 + iw * 16 + il;
            const int jbase = j0 + jh * 32 + lo4;
            float s0 = (jbase      <= ig + CM) ? (sa[0][r] + rel0) : -1e30f;
            float s1 = (jbase + 16 <= ig + CM) ? (sa[1][r] + rel1) : -1e30f;
            float tm = fmaxf(s0, s1);
            #pragma unroll
            for (int off = 1; off < 16; off <<= 1) tm = fmaxf(tm, __shfl_xor(tm, off));
            const float mn = fmaxf(mr[r], tm);
            const float scl = __expf(mr[r] - mn);
            mr[r] = mn;
            Pl[w][il][lo4]      = f2bf(__expf(s0 - mn));
            Pl[w][il][16 + lo4] = f2bf(__expf(s1 - mn));
            #pragma unroll
            for (int n = 0; n < 5; ++n) oacc[n][r] *= scl;
        }

        // ---- PV (+ones): O += P·V, l += P·1
        __builtin_amdgcn_s_setprio(1);
        {
            short8 pa = *(const short8*)&Pl[w][lo4][g * 8];
            #pragma unroll
            for (int n = 0; n < 4; ++n) {
                short8 vb = *(const short8*)&Vt[n * 16 + lo4][jh * 32 + g * 8];
                oacc[n] = __builtin_amdgcn_mfma_f32_16x16x32_bf16(pa, vb, oacc[n], 0, 0, 0);
            }
            short8 vo = *(const short8*)&Vt[64 + lo4][jh * 32 + g * 8];
            oacc[4] = __builtin_amdgcn_mfma_f32_16x16x32_bf16(pa, vo, oacc[4], 0, 0, 0);
        }
        __builtin_amdgcn_s_setprio(0);
    }

    // ---- merge j-halves in-block, write partial (O,m,l) to pw
    __syncthreads();
    float* oTmp = (float*)&Rs[0];          // 8 KB of the 12 KB Rs region
    if (jh == 1) {
        #pragma unroll
        for (int r = 0; r < 4; ++r) {
            const int il = 4 * g + r;
            #pragma unroll
            for (int n = 0; n < 4; ++n)
                oTmp[((iw * 16 + il) << 6) + n * 16 + lo4] = oacc[n][r];
            if (lo4 == 0) { mB[iw][il] = mr[r]; lB[iw][il] = oacc[4][r]; }
        }
    }
    __syncthreads();
    if (jh == 0) {
        float* pwp = pw + ((size_t)(((bb * CH + hh) * 16 + zt) * 2 + js)) * 2112;
        #pragma unroll
        for (int r = 0; r < 4; ++r) {
            const int il = 4 * g + r;
            const int row = iw * 16 + il;
            const float mBv = mB[iw][il], lBv = lB[iw][il];
            const float ms = fmaxf(mr[r], mBv);
            const float fA = __expf(mr[r] - ms);
            const float fB = __expf(mBv - ms);
            const float lt = oacc[4][r] * fA + lBv * fB;
            #pragma unroll
            for (int n = 0; n < 4; ++n)
                pwp[(row << 6) + n * 16 + lo4] =
                    oacc[n][r] * fA + oTmp[(row << 6) + n * 16 + lo4] * fB;
            if (lo4 == 0) { pwp[2048 + row] = ms; pwp[2048 + 32 + row] = lt; }
        }
    }
}

// ---------------- merge the two split-j partials -> bf16 output
__global__ __launch_bounds__(256)
void attn_merge(const float* __restrict__ pw, ushort* __restrict__ outm) {
    const int zt = blockIdx.x, hh = blockIdx.y, bb = blockIdx.z;
    const int tid = threadIdx.x;
    const int row = tid >> 3, c8 = tid & 7;
    const float* pA = pw + ((size_t)(((bb * CH + hh) * 16 + zt) * 2 + 0)) * 2112;
    const float* pB = pA + 2112;
    const float mA = pA[2048 + row], lA = pA[2048 + 32 + row];
    const float mBv = pB[2048 + row], lBv = pB[2048 + 32 + row];
    const float ms = fmaxf(mA, mBv);
    const float fA = __expf(mA - ms);
    const float fB = __expf(mBv - ms);
    const float invl = 1.0f / (lA * fA + lBv * fB);
    float4 a0 = *(const float4*)&pA[(row << 6) + c8 * 8];
    float4 a1 = *(const float4*)&pA[(row << 6) + c8 * 8 + 4];
    float4 b0 = *(const float4*)&pB[(row << 6) + c8 * 8];
    float4 b1 = *(const float4*)&pB[(row << 6) + c8 * 8 + 4];
    union { ushort us[8]; uint4 q; } pk;
    pk.us[0] = f2bf((a0.x * fA + b0.x * fB) * invl);
    pk.us[1] = f2bf((a0.y * fA + b0.y * fB) * invl);
    pk.us[2] = f2bf((a0.z * fA + b0.z * fB) * invl);
    pk.us[3] = f2bf((a0.w * fA + b0.w * fB) * invl);
    pk.us[4] = f2bf((a1.x * fA + b1.x * fB) * invl);
    pk.us[5] = f2bf((a1.y * fA + b1.y * fB) * invl);
    pk.us[6] = f2bf((a1.z * fA + b1.z * fB) * invl);
    pk.us[7] = f2bf((a1.w * fA + b1.w * fB) * invl);
    *(uint4*)&outm[((size_t)(bb * CS + zt * 32 + row)) * CD + hh * CDK + c8 * 8] = pk.q;
}

// ---------------- residual + 2 partials (+row bias) + layernorm, dual output
__global__ __launch_bounds__(256)
void ln_kernel(const float* __restrict__ a, const float* __restrict__ p0,
               const float* __restrict__ p1, const float* __restrict__ bias,
               const float* __restrict__ g, const float* __restrict__ beta,
               float* __restrict__ out, ushort* __restrict__ outbf)
{
    const int row = blockIdx.x;
    const int tid = threadIdx.x;
    const size_t base = (size_t)row * CD;
    float4 xa = *(const float4*)&a[base + tid * 4];
    float4 x0v = *(const float4*)&p0[base + tid * 4];
    float4 x1v = *(const float4*)&p1[base + tid * 4];
    float4 bb = bias ? *(const float4*)&bias[tid * 4] : make_float4(0.f, 0.f, 0.f, 0.f);
    float x0 = xa.x + x0v.x + x1v.x + bb.x;
    float x1 = xa.y + x0v.y + x1v.y + bb.y;
    float x2 = xa.z + x0v.z + x1v.z + bb.z;
    float x3 = xa.w + x0v.w + x1v.w + bb.w;
    float sum = x0 + x1 + x2 + x3;
    float sq  = x0 * x0 + x1 * x1 + x2 * x2 + x3 * x3;
    #pragma unroll
    for (int off = 1; off < 64; off <<= 1) {
        sum += __shfl_xor(sum, off);
        sq  += __shfl_xor(sq, off);
    }
    __shared__ float ssum[4], ssq[4];
    const int wid = tid >> 6;
    if ((tid & 63) == 0) { ssum[wid] = sum; ssq[wid] = sq; }
    __syncthreads();
    sum = ssum[0] + ssum[1] + ssum[2] + ssum[3];
    sq  = ssq[0] + ssq[1] + ssq[2] + ssq[3];
    const float mean = sum * (1.0f / CD);
    const float var  = sq * (1.0f / CD) - mean * mean;
    const float rstd = rsqrtf(var + 1e-5f);
    float4 gv = *(const float4*)&g[tid * 4];
    float4 bv = *(const float4*)&beta[tid * 4];
    float4 r;
    r.x = (x0 - mean) * rstd * gv.x + bv.x;
    r.y = (x1 - mean) * rstd * gv.y + bv.y;
    r.z = (x2 - mean) * rstd * gv.z + bv.z;
    r.w = (x3 - mean) * rstd * gv.w + bv.w;
    *(float4*)&out[base + tid * 4] = r;
    if (outbf) {
        union { ushort us[4]; uint2 q; } pk;
        pk.us[0] = f2bf(r.x); pk.us[1] = f2bf(r.y); pk.us[2] = f2bf(r.z); pk.us[3] = f2bf(r.w);
        *(uint2*)&outbf[base + tid * 4] = pk.q;
    }
}

extern "C" void kernel_launch(void* const* d_in, const int* in_sizes, int n_in,
                              void* d_out, int out_size, void* d_ws, size_t ws_size,
                              hipStream_t stream) {
    const float* x    = (const float*)d_in[0];
    const float* memL = (const float*)d_in[1];
    const float* Wq   = (const float*)d_in[2];
    const float* Wk   = (const float*)d_in[3];
    const float* Wv   = (const float*)d_in[4];
    const float* Wr   = (const float*)d_in[5];
    const float* Wo   = (const float*)d_in[6];
    const float* rwb  = (const float*)d_in[7];
    const float* rrb  = (const float*)d_in[8];
    const float* ln1g = (const float*)d_in[9];
    const float* ln1b = (const float*)d_in[10];
    const float* ln2g = (const float*)d_in[11];
    const float* ln2b = (const float*)d_in[12];
    const float* W1   = (const float*)d_in[13];
    const float* b1   = (const float*)d_in[14];
    const float* W2   = (const float*)d_in[15];
    const float* b2   = (const float*)d_in[16];

    const size_t MEG = 1048576;
    float* h      = (float*)d_ws;                 // 1M f32
    float* p0     = h + MEG;                      // 1M f32
    float* p1     = p0 + MEG;                     // 1M f32
    float* pw     = p1 + MEG;                     // 1024 x 2112 f32
    ushort* hbf   = (ushort*)(pw + 1024 * 2112);  // 1M us  (contiguous h, bf16)
    ushort* membf = hbf + MEG;                    // 4M us  [L][B*M][D]
    ushort* kvmem = membf + 4 * MEG;              // 8M us  [L][B*M][2048] k|v
    ushort* hproj = kvmem + 8 * MEG;              // 3M us  [B*S][3072] q|k|v
    ushort* attbf = hproj + 3 * MEG;              // 1M us
    ushort* ff1bf = attbf + MEG;                  // 4M us
    ushort* posbf = ff1bf + 4 * MEG;              // 1M us
    ushort* r_all = posbf + MEG;                  // 4M us  [L][T][D]
    ushort* wqkvT = r_all + 4 * MEG;              // 12M us [L][3D][D]
    ushort* wrT   = wqkvT + 12 * MEG;             // 4M us
    ushort* woT   = wrT + 4 * MEG;                // 4M us
    ushort* w1T   = woT + 4 * MEG;                // 16M us [L][FF][D]
    ushort* w2T   = w1T + 16 * MEG;               // 16M us [L][D][FF]
    // total ~180 MB (ws ~268 MB)

    const size_t WD = (size_t)CD * CD;

    // ---------- loop-invariant preamble ----------
    pos_kernel<<<(CT * (CD / 2)) / 256, 256, 0, stream>>>(posbf);
    cvt_bf16_kernel<<<(CL * CB * CM * CD / 8) / 256, 256, 0, stream>>>(
        memL, membf, CL * CB * CM * CD / 8);
    cvt_bf16_kernel<<<(CB * CS * CD / 8) / 256, 256, 0, stream>>>(
        x, hbf, CB * CS * CD / 8);
    transpose_w5<<<dim3(16, 16, 5 * CL), 256, 0, stream>>>(Wq, Wk, Wv, Wr, Wo, wqkvT, wrT, woT);
    transpose_cvt<<<dim3(64, 16, CL), 256, 0, stream>>>(W1, w1T, CD, CFF, 4 * WD, 4 * WD);
    transpose_cvt<<<dim3(16, 64, CL), 256, 0, stream>>>(W2, w2T, CFF, CD, 4 * WD, 4 * WD);
    // r_all[l] = pos @ Wr_l  (batched over z = layer); chunks 4x8
    gemm_bf16<64, 64><<<dim3(16, 16, CL), 256, 0, stream>>>(
        posbf, wrT, nullptr, r_all, CD, CD, CD, 4, 8, 0, WD, (size_t)CT * CD,
        nullptr, 1.0f, 0);
    // kvmem[l] = mem_l @ [Wk|Wv]_l  (batched over z = layer); chunks 4x8
    gemm_bf16<64, 128><<<dim3(16, 16, CL), 256, 0, stream>>>(
        membf, wqkvT + WD, nullptr, kvmem,
        2 * CD, CD, CD, 4, 8, MEG, 3 * WD, 2 * MEG, nullptr, 1.0f, 0);

    // ---------- layer loop ----------
    for (int l = 0; l < CL; ++l) {
        const float* hin = (l == 0) ? x : h;

        // hproj = h @ [Wq|Wk|Wv]_l  -> bf16 [1024 x 3072]; chunks 6x8
        gemm_bf16<64, 128><<<dim3(24, 16), 256, 0, stream>>>(
            hbf, wqkvT + (size_t)l * 3 * WD, nullptr, hproj,
            3 * CD, CD, CD, 6, 8, 0, 0, 0, nullptr, 1.0f, 0);

        // fused relative attention (split-j) -> partials -> merge -> bf16
        attn_kernel<<<dim3(2 * CS / 32, CH, CB), 256, 0, stream>>>(
            hproj, kvmem + (size_t)l * 2 * MEG, r_all + (size_t)l * CT * CD,
            rwb + (size_t)l * CH * CDK, rrb + (size_t)l * CH * CDK, pw);
        attn_merge<<<dim3(CS / 32, CH, CB), 256, 0, stream>>>(pw, attbf);

        // merge linear (split-K=2 -> p0,p1) + LN1; chunks 4x8
        gemm_bf16<64, 64><<<dim3(16, 16, 2), 256, 0, stream>>>(
            attbf, woT + (size_t)l * WD, p0, nullptr,
            CD, CD / 2, CD, 4, 8, CD / 2, CD / 2, MEG, nullptr, 1.0f, 0);
        ln_kernel<<<CB * CS, 256, 0, stream>>>(
            hin, p0, p1, nullptr, ln1g + (size_t)l * CD, ln1b + (size_t)l * CD, h, hbf);

        // FF: relu(h@W1+b1) -> ff1bf (chunks 8x8); ff1@W2 split-K=2 (chunks 4x8); LN2
        gemm_bf16<64, 128><<<dim3(32, 16), 256, 0, stream>>>(
            hbf, w1T + (size_t)l * 4 * WD, nullptr, ff1bf,
            CFF, CD, CD, 8, 8, 0, 0, 0, b1 + (size_t)l * CFF, 1.0f, 1);
        gemm_bf16<64, 64><<<dim3(16, 16, 2), 256, 0, stream>>>(
            ff1bf, w2T + (size_t)l * 4 * WD, p0, nullptr,
            CD, CFF / 2, CFF, 4, 8, CFF / 2, CFF / 2, MEG, nullptr, 1.0f, 0);
        ln_kernel<<<CB * CS, 256, 0, stream>>>(
            h, p0, p1, b2 + (size_t)l * CD, ln2g + (size_t)l * CD, ln2b + (size_t)l * CD,
            (l == CL - 1) ? (float*)d_out : h,
            (l == CL - 1) ? nullptr : hbf);
    }
}